// Round 5
// baseline (67.614 us; speedup 1.0000x reference)
//
#include <hip/hip_runtime.h>

namespace {
constexpr int Bn = 32, Dn = 64, Hn = 64, Wn = 64;
constexpr int PLANE = Hn * Wn;   // 4096
constexpr int NW  = 8;           // waves per block, splitting d
constexpr int DPW = Dn / NW;     // 8 d-slices per wave
constexpr float SCALE = 0.125f;  // 64^-0.5
typedef float f4a __attribute__((ext_vector_type(4), aligned(4)));
}

__global__ __launch_bounds__(512, 8) void dilate_attn_kernel(
    const float* __restrict__ q, const float* __restrict__ k,
    const float* __restrict__ v, float* __restrict__ out)
{
    __shared__ float2 red[NW][9][64];   // 36864 B; 4 blocks/CU = 147 KB

    const int t  = threadIdx.x;
    const int l  = t & 63;
    const int wv = t >> 6;              // wave id -> d-eighth
    const int ci = l & 31;              // lane col-pair index
    const int lr = l >> 5;              // row within stripe
    const int c  = ci * 2;              // first of this lane's 2 pixel cols

    // XCD-chunked swizzle: 1024 blocks -> 128 contiguous (b,stripe) per XCD
    const int bid = blockIdx.x;
    const int swz = (bid & 7) * 128 + (bid >> 3);
    const int b      = swz >> 5;
    const int stripe = swz & 31;
    const int hr     = stripe * 2 + lr; // this lane's pixel row

    const int  base = b * Dn * PLANE;
    const bool ci0 = (ci == 0), ci31 = (ci == 31);
    const int  cb = ci0 ? 0 : (ci31 ? (c - 2) : (c - 1));

    int  koff[3];
    bool rok[3];
#pragma unroll
    for (int di = 0; di < 3; ++di) {
        const int kr = hr - 1 + di;
        rok[di] = (kr >= 0) && (kr < Hn);
        const int krc = min(max(kr, 0), Hn - 1);   // clamped: always in-bounds
        koff[di] = krc * Wn + cb;
    }
    const int qoff = hr * Wn + c;

    float a0[9], a1[9];
#pragma unroll
    for (int n = 0; n < 9; ++n) { a0[n] = 0.0f; a1[n] = 0.0f; }

    // -------- Phase 1: partial scores over this wave's 8 d-slices ----------
    {
        const float* kp = k + base + wv * DPW * PLANE;
        const float* qp = q + base + wv * DPW * PLANE + qoff;

        f4a x0, x1, x2; float2 xq;
        f4a y0, y1, y2; float2 yq;

        auto LDK = [&](int ds, f4a& r0, f4a& r1, f4a& r2, float2& qv) {
            const float* kk = kp + ds * PLANE;
            r0 = *(const f4a*)(kk + koff[0]);
            r1 = *(const f4a*)(kk + koff[1]);
            r2 = *(const f4a*)(kk + koff[2]);
            qv = *(const float2*)(qp + ds * PLANE);
        };
        auto ACC = [&](const f4a& r0, const f4a& r1, const f4a& r2,
                       const float2& qv) {
#pragma unroll
            for (int di = 0; di < 3; ++di) {
                const f4a vv = (di == 0) ? r0 : (di == 1) ? r1 : r2;
                const float w0 = ci31 ? vv.y : vv.x;
                const float w1 = ci0 ? vv.x : (ci31 ? vv.z : vv.y);
                const float w2 = ci0 ? vv.y : (ci31 ? vv.w : vv.z);
                const float w3 = ci0 ? vv.z : vv.w;
                a0[di * 3 + 0] = fmaf(qv.x, w0, a0[di * 3 + 0]);
                a0[di * 3 + 1] = fmaf(qv.x, w1, a0[di * 3 + 1]);
                a0[di * 3 + 2] = fmaf(qv.x, w2, a0[di * 3 + 2]);
                a1[di * 3 + 0] = fmaf(qv.y, w1, a1[di * 3 + 0]);
                a1[di * 3 + 1] = fmaf(qv.y, w2, a1[di * 3 + 1]);
                a1[di * 3 + 2] = fmaf(qv.y, w3, a1[di * 3 + 2]);
            }
        };

        LDK(0, x0, x1, x2, xq);
#pragma unroll
        for (int ds = 0; ds < DPW; ds += 2) {
            if (ds + 1 < DPW) LDK(ds + 1, y0, y1, y2, yq);
            ACC(x0, x1, x2, xq);
            if (ds + 2 < DPW) LDK(ds + 2, x0, x1, x2, xq);
            if (ds + 1 < DPW) ACC(y0, y1, y2, yq);
        }
    }

    // -------- cross-wave reduction: wave wv owns window position n=wv ------
#pragma unroll
    for (int n = 0; n < 9; ++n) red[wv][n][l] = make_float2(a0[n], a1[n]);
    __syncthreads();
    {
        float2 s = red[0][wv][l];
#pragma unroll
        for (int sw = 1; sw < NW; ++sw) {
            const float2 p = red[sw][wv][l];
            s.x += p.x; s.y += p.y;
        }
        red[0][wv][l] = s;
        if (wv == NW - 1) {          // wave 7 also reduces n=8
            float2 s8 = red[0][8][l];
#pragma unroll
            for (int sw = 1; sw < NW; ++sw) {
                const float2 p = red[sw][8][l];
                s8.x += p.x; s8.y += p.y;
            }
            red[0][8][l] = s8;
        }
    }
    __syncthreads();
#pragma unroll
    for (int n = 0; n < 9; ++n) {
        const float2 s = red[0][n][l];
        a0[n] = s.x; a1[n] = s.y;
    }

    // -------- zero invalid-position SCORES (reference: q . 0-pad = 0) -------
#pragma unroll
    for (int di = 0; di < 3; ++di)
#pragma unroll
        for (int dj = 0; dj < 3; ++dj) {
            const int n = di * 3 + dj;
            a0[n] = (rok[di] && (dj != 0 || !ci0))  ? a0[n] : 0.0f;
            a1[n] = (rok[di] && (dj != 2 || !ci31)) ? a1[n] : 0.0f;
        }
#pragma unroll
    for (int n = 0; n < 9; ++n) { a0[n] *= SCALE; a1[n] *= SCALE; }
    float m0 = a0[0], m1 = a1[0];
#pragma unroll
    for (int n = 1; n < 9; ++n) { m0 = fmaxf(m0, a0[n]); m1 = fmaxf(m1, a1[n]); }
    float s0 = 0.0f, s1 = 0.0f;
#pragma unroll
    for (int n = 0; n < 9; ++n) {
        a0[n] = __expf(a0[n] - m0); s0 += a0[n];
        a1[n] = __expf(a1[n] - m1); s1 += a1[n];
    }
    const float i0 = 1.0f / s0, i1 = 1.0f / s1;
#pragma unroll
    for (int n = 0; n < 9; ++n) { a0[n] *= i0; a1[n] *= i1; }

    // -------- zero invalid-position WEIGHTS (reference: attn * v=0 there) ---
#pragma unroll
    for (int di = 0; di < 3; ++di)
#pragma unroll
        for (int dj = 0; dj < 3; ++dj) {
            const int n = di * 3 + dj;
            a0[n] = (rok[di] && (dj != 0 || !ci0))  ? a0[n] : 0.0f;
            a1[n] = (rok[di] && (dj != 2 || !ci31)) ? a1[n] : 0.0f;
        }

    // -------- Phase 2: out = attn . v_window for this wave's d-eighth -------
    {
        const float* vp = v + base + wv * DPW * PLANE;
        float*       op = out + base + wv * DPW * PLANE + qoff;

        f4a x0, x1, x2;
        f4a y0, y1, y2;

        auto LDV = [&](int ds, f4a& r0, f4a& r1, f4a& r2) {
            const float* vk = vp + ds * PLANE;
            r0 = *(const f4a*)(vk + koff[0]);
            r1 = *(const f4a*)(vk + koff[1]);
            r2 = *(const f4a*)(vk + koff[2]);
        };
        auto PV = [&](int ds, const f4a& r0, const f4a& r1, const f4a& r2) {
            float o0 = 0.0f, o1 = 0.0f;
#pragma unroll
            for (int di = 0; di < 3; ++di) {
                const f4a vv = (di == 0) ? r0 : (di == 1) ? r1 : r2;
                const float w0 = ci31 ? vv.y : vv.x;
                const float w1 = ci0 ? vv.x : (ci31 ? vv.z : vv.y);
                const float w2 = ci0 ? vv.y : (ci31 ? vv.w : vv.z);
                const float w3 = ci0 ? vv.z : vv.w;
                o0 = fmaf(a0[di * 3 + 0], w0, o0);
                o0 = fmaf(a0[di * 3 + 1], w1, o0);
                o0 = fmaf(a0[di * 3 + 2], w2, o0);
                o1 = fmaf(a1[di * 3 + 0], w1, o1);
                o1 = fmaf(a1[di * 3 + 1], w2, o1);
                o1 = fmaf(a1[di * 3 + 2], w3, o1);
            }
            *(float2*)(op + ds * PLANE) = make_float2(o0, o1);
        };

        LDV(0, x0, x1, x2);
#pragma unroll
        for (int ds = 0; ds < DPW; ds += 2) {
            if (ds + 1 < DPW) LDV(ds + 1, y0, y1, y2);
            PV(ds, x0, x1, x2);
            if (ds + 2 < DPW) LDV(ds + 2, x0, x1, x2);
            if (ds + 1 < DPW) PV(ds + 1, y0, y1, y2);
        }
    }
}

extern "C" void kernel_launch(void* const* d_in, const int* in_sizes, int n_in,
                              void* d_out, int out_size, void* d_ws, size_t ws_size,
                              hipStream_t stream) {
    const float* q = (const float*)d_in[0];
    const float* k = (const float*)d_in[1];
    const float* v = (const float*)d_in[2];
    float* out = (float*)d_out;
    (void)in_sizes; (void)n_in; (void)out_size; (void)d_ws; (void)ws_size;

    const int grid = Bn * 32;  // 1024 blocks x 512 thr -> 4/CU, 32 waves/CU
    dilate_attn_kernel<<<grid, 512, 0, stream>>>(q, k, v, out);
}

// Round 6
// 26.762 us; speedup vs baseline: 2.5265x; 2.5265x over previous
//
#include <hip/hip_runtime.h>

namespace {
constexpr int Bn = 32, Dn = 64, Hn = 64, Wn = 64;
constexpr int PLANE = Hn * Wn;   // 4096
constexpr int NW  = 8;           // waves per block, splitting d
constexpr int DPW = Dn / NW;     // 8 d-slices per wave
constexpr float SCALE = 0.125f;  // 64^-0.5
typedef float f4a __attribute__((ext_vector_type(4), aligned(4)));
}

__global__ __launch_bounds__(512, 8) void dilate_attn_kernel(
    const float* __restrict__ q, const float* __restrict__ k,
    const float* __restrict__ v, float* __restrict__ out)
{
    __shared__ float2 red[NW][9][64];   // 36864 B; 4 blocks/CU = 147 KB

    const int t  = threadIdx.x;
    const int l  = t & 63;
    const int wv = t >> 6;              // wave id -> d-eighth
    const int ci = l & 31;              // lane col-pair index
    const int lr = l >> 5;              // row within stripe
    const int c  = ci * 2;              // first of this lane's 2 pixel cols

    // XCD-chunked swizzle: 1024 blocks -> 128 contiguous (b,stripe) per XCD
    const int bid = blockIdx.x;
    const int swz = (bid & 7) * 128 + (bid >> 3);
    const int b      = swz >> 5;
    const int stripe = swz & 31;
    const int hr     = stripe * 2 + lr; // this lane's pixel row

    const int  base = b * Dn * PLANE;
    const bool ci0 = (ci == 0), ci31 = (ci == 31);
    const int  cb = ci0 ? 0 : (ci31 ? (c - 2) : (c - 1));

    int  koff[3];
    bool rok[3];
#pragma unroll
    for (int di = 0; di < 3; ++di) {
        const int kr = hr - 1 + di;
        rok[di] = (kr >= 0) && (kr < Hn);
        const int krc = min(max(kr, 0), Hn - 1);   // clamped: always in-bounds
        koff[di] = krc * Wn + cb;
    }
    const int qoff = hr * Wn + c;

    float a0[9], a1[9];
#pragma unroll
    for (int n = 0; n < 9; ++n) { a0[n] = 0.0f; a1[n] = 0.0f; }

    // -------- Phase 1: partial scores over this wave's 8 d-slices ----------
    {
        const float* kp = k + base + wv * DPW * PLANE;
        const float* qp = q + base + wv * DPW * PLANE;
#pragma unroll 4
        for (int ds = 0; ds < DPW; ++ds) {
            const f4a r0 = *(const f4a*)(kp + koff[0]);
            const f4a r1 = *(const f4a*)(kp + koff[1]);
            const f4a r2 = *(const f4a*)(kp + koff[2]);
            const float2 qv = *(const float2*)(qp + qoff);
            kp += PLANE; qp += PLANE;
#pragma unroll
            for (int di = 0; di < 3; ++di) {
                const f4a vv = (di == 0) ? r0 : (di == 1) ? r1 : r2;
                const float w0 = ci31 ? vv.y : vv.x;
                const float w1 = ci0 ? vv.x : (ci31 ? vv.z : vv.y);
                const float w2 = ci0 ? vv.y : (ci31 ? vv.w : vv.z);
                const float w3 = ci0 ? vv.z : vv.w;
                a0[di * 3 + 0] = fmaf(qv.x, w0, a0[di * 3 + 0]);
                a0[di * 3 + 1] = fmaf(qv.x, w1, a0[di * 3 + 1]);
                a0[di * 3 + 2] = fmaf(qv.x, w2, a0[di * 3 + 2]);
                a1[di * 3 + 0] = fmaf(qv.y, w1, a1[di * 3 + 0]);
                a1[di * 3 + 1] = fmaf(qv.y, w2, a1[di * 3 + 1]);
                a1[di * 3 + 2] = fmaf(qv.y, w3, a1[di * 3 + 2]);
            }
        }
    }

    // -------- cross-wave reduction: wave wv owns window position n=wv ------
#pragma unroll
    for (int n = 0; n < 9; ++n) red[wv][n][l] = make_float2(a0[n], a1[n]);
    __syncthreads();
    {
        float2 s = red[0][wv][l];
#pragma unroll
        for (int sw = 1; sw < NW; ++sw) {
            const float2 p = red[sw][wv][l];
            s.x += p.x; s.y += p.y;
        }
        red[0][wv][l] = s;
        if (wv == NW - 1) {          // wave 7 also reduces n=8
            float2 s8 = red[0][8][l];
#pragma unroll
            for (int sw = 1; sw < NW; ++sw) {
                const float2 p = red[sw][8][l];
                s8.x += p.x; s8.y += p.y;
            }
            red[0][8][l] = s8;
        }
    }
    __syncthreads();
#pragma unroll
    for (int n = 0; n < 9; ++n) {
        const float2 s = red[0][n][l];
        a0[n] = s.x; a1[n] = s.y;
    }

    // -------- zero invalid-position SCORES (reference: q . 0-pad = 0) -------
#pragma unroll
    for (int di = 0; di < 3; ++di)
#pragma unroll
        for (int dj = 0; dj < 3; ++dj) {
            const int n = di * 3 + dj;
            a0[n] = (rok[di] && (dj != 0 || !ci0))  ? a0[n] : 0.0f;
            a1[n] = (rok[di] && (dj != 2 || !ci31)) ? a1[n] : 0.0f;
        }
#pragma unroll
    for (int n = 0; n < 9; ++n) { a0[n] *= SCALE; a1[n] *= SCALE; }
    float m0 = a0[0], m1 = a1[0];
#pragma unroll
    for (int n = 1; n < 9; ++n) { m0 = fmaxf(m0, a0[n]); m1 = fmaxf(m1, a1[n]); }
    float s0 = 0.0f, s1 = 0.0f;
#pragma unroll
    for (int n = 0; n < 9; ++n) {
        a0[n] = __expf(a0[n] - m0); s0 += a0[n];
        a1[n] = __expf(a1[n] - m1); s1 += a1[n];
    }
    const float i0 = 1.0f / s0, i1 = 1.0f / s1;
#pragma unroll
    for (int n = 0; n < 9; ++n) { a0[n] *= i0; a1[n] *= i1; }

    // -------- zero invalid-position WEIGHTS (reference: attn * v=0 there) ---
#pragma unroll
    for (int di = 0; di < 3; ++di)
#pragma unroll
        for (int dj = 0; dj < 3; ++dj) {
            const int n = di * 3 + dj;
            a0[n] = (rok[di] && (dj != 0 || !ci0))  ? a0[n] : 0.0f;
            a1[n] = (rok[di] && (dj != 2 || !ci31)) ? a1[n] : 0.0f;
        }

    // -------- Phase 2: out = attn . v_window for this wave's d-eighth -------
    {
        const float* vp = v + base + wv * DPW * PLANE;
        float*       op = out + base + wv * DPW * PLANE;
#pragma unroll 4
        for (int ds = 0; ds < DPW; ++ds) {
            const f4a r0 = *(const f4a*)(vp + koff[0]);
            const f4a r1 = *(const f4a*)(vp + koff[1]);
            const f4a r2 = *(const f4a*)(vp + koff[2]);
            vp += PLANE;
            float o0 = 0.0f, o1 = 0.0f;
#pragma unroll
            for (int di = 0; di < 3; ++di) {
                const f4a vv = (di == 0) ? r0 : (di == 1) ? r1 : r2;
                const float w0 = ci31 ? vv.y : vv.x;
                const float w1 = ci0 ? vv.x : (ci31 ? vv.z : vv.y);
                const float w2 = ci0 ? vv.y : (ci31 ? vv.w : vv.z);
                const float w3 = ci0 ? vv.z : vv.w;
                o0 = fmaf(a0[di * 3 + 0], w0, o0);
                o0 = fmaf(a0[di * 3 + 1], w1, o0);
                o0 = fmaf(a0[di * 3 + 2], w2, o0);
                o1 = fmaf(a1[di * 3 + 0], w1, o1);
                o1 = fmaf(a1[di * 3 + 1], w2, o1);
                o1 = fmaf(a1[di * 3 + 2], w3, o1);
            }
            *(float2*)(op + qoff) = make_float2(o0, o1);
            op += PLANE;
        }
    }
}

extern "C" void kernel_launch(void* const* d_in, const int* in_sizes, int n_in,
                              void* d_out, int out_size, void* d_ws, size_t ws_size,
                              hipStream_t stream) {
    const float* q = (const float*)d_in[0];
    const float* k = (const float*)d_in[1];
    const float* v = (const float*)d_in[2];
    float* out = (float*)d_out;
    (void)in_sizes; (void)n_in; (void)out_size; (void)d_ws; (void)ws_size;

    const int grid = Bn * 32;  // 1024 blocks x 512 thr -> 4/CU, 32 waves/CU
    dilate_attn_kernel<<<grid, 512, 0, stream>>>(q, k, v, out);
}